// Round 6
// baseline (126.477 us; speedup 1.0000x reference)
//
#include <hip/hip_runtime.h>
#include <math.h>

#define N_NODES 32
#define DIM     128
#define NBLK    32
#define NTHR_G  768   // 32 (node/src) x 4 (dims) x 6 (gate rows)
#define NTHR_H  256
#define HIST_BLOCKS 64
#define SH_PAD  132   // padded row stride (floats) for bank-conflict-free b128

struct GnnParams {
  const int* nt; const int* tr;
  const float* ne_w; const float* te_w; const float* ef_w;
  const float* w_ih; const float* w_hh; const float* b_ih; const float* b_hh;
  const float* ln_g; const float* ln_b;
  const float* fc1_w; const float* fc1_b;
  const float* ln2_g; const float* ln2_b;
  const float* fc2_w; const float* fc2_b;
  const int* hA; const int* hF;
  int* bar;
  float* hp0; float* hp1;   // pre-LN h exchange (ping-pong) [32*128]
  float* ps0; float* ps1;   // partials: [ps(1024) | pq(1024)] contiguous each
  float* out;
};

// ---- lightweight grid barrier: NO threadfence (no L2 invalidation) ---------
__device__ __forceinline__ void grid_barrier(int* bar) {
  asm volatile("s_waitcnt vmcnt(0)" ::: "memory");  // drain sc1 stores
  __syncthreads();
  if (threadIdx.x == 0) {
    int gen = __hip_atomic_load(&bar[1], __ATOMIC_RELAXED, __HIP_MEMORY_SCOPE_AGENT);
    int arrived = __hip_atomic_fetch_add(&bar[0], 1, __ATOMIC_RELAXED,
                                         __HIP_MEMORY_SCOPE_AGENT);
    if (arrived == NBLK - 1) {
      __hip_atomic_store(&bar[0], 0, __ATOMIC_RELAXED, __HIP_MEMORY_SCOPE_AGENT);
      __hip_atomic_fetch_add(&bar[1], 1, __ATOMIC_RELEASE, __HIP_MEMORY_SCOPE_AGENT);
    } else {
      while (__hip_atomic_load(&bar[1], __ATOMIC_RELAXED,
                               __HIP_MEMORY_SCOPE_AGENT) == gen)
        __builtin_amdgcn_s_sleep(1);
    }
  }
  __syncthreads();
}

__device__ __forceinline__ void st_sc1(float* p, float v) {
  __hip_atomic_store(p, v, __ATOMIC_RELAXED, __HIP_MEMORY_SCOPE_AGENT);
}
__device__ __forceinline__ unsigned long long ld8_sc1(const unsigned long long* p) {
  return __hip_atomic_load(p, __ATOMIC_RELAXED, __HIP_MEMORY_SCOPE_AGENT);
}

// ---------------- histogram over edges (index-only, loop-invariant) ---------
__global__ __launch_bounds__(NTHR_H) void hist_kernel(
    const int* __restrict__ es, const int* __restrict__ ed,
    const int* __restrict__ ef, int E,
    int* __restrict__ hA, int* __restrict__ hF)
{
  __shared__ int lA[N_NODES * N_NODES];
  __shared__ int lF[N_NODES * 6];
  const int t = threadIdx.x;
  for (int i = t; i < N_NODES * N_NODES; i += NTHR_H) lA[i] = 0;
  for (int i = t; i < N_NODES * 6;       i += NTHR_H) lF[i] = 0;
  __syncthreads();

  const int E4 = E >> 2;
  const int4* es4 = (const int4*)es;
  const int4* ed4 = (const int4*)ed;
  const int4* ef4 = (const int4*)ef;
  #define DO_EDGE(S, D, F) \
    if ((unsigned)(S) < N_NODES && (unsigned)(D) < N_NODES) { \
      atomicAdd(&lA[(D) * N_NODES + (S)], 1); \
      atomicAdd(&lF[(D) * 6 + (F)], 1); }
  for (int i = blockIdx.x * NTHR_H + t; i < E4; i += gridDim.x * NTHR_H) {
    int4 s4 = es4[i], d4 = ed4[i], f4 = ef4[i];
    DO_EDGE(s4.x, d4.x, f4.x)
    DO_EDGE(s4.y, d4.y, f4.y)
    DO_EDGE(s4.z, d4.z, f4.z)
    DO_EDGE(s4.w, d4.w, f4.w)
  }
  if (blockIdx.x == 0) {
    for (int e = (E4 << 2) + t; e < E; e += NTHR_H) {
      int s = es[e], d = ed[e], f = ef[e];
      DO_EDGE(s, d, f)
    }
  }
  #undef DO_EDGE
  __syncthreads();
  for (int i = t; i < N_NODES * N_NODES; i += NTHR_H) { int v = lA[i]; if (v) atomicAdd(&hA[i], v); }
  for (int i = t; i < N_NODES * 6;       i += NTHR_H) { int v = lF[i]; if (v) atomicAdd(&hF[i], v); }
}

// --------- GRU kernel: block owns 4 output dims; weights live in VGPRs ------
__global__ __launch_bounds__(NTHR_G) void gnn_kernel(GnnParams p)
{
  const int b = blockIdx.x;          // owns dims [4b, 4b+4)
  const int t = threadIdx.x;
  const int u  = t / 24;             // node (hh dots) or src (gih dots), 0..31
  const int r  = t - u * 24;         // 0..23
  const int dl = r / 6;              // local dim 0..3
  const int g  = r - dl * 6;         // gate row: 0..2 = ih(r,z,n), 3..5 = hh
  const int d  = b * 4 + dl;         // global dim

  __shared__ float sh[N_NODES][SH_PAD];     // post-LN h (padded rows)
  __shared__ float sB[N_NODES][DIM];        // B = F @ ef_w (loop-invariant)
  __shared__ float hps[N_NODES * DIM];      // staged pre-LN h
  __shared__ float sAT[N_NODES * N_NODES];  // A transposed: sAT[s*32+n]
  __shared__ float spart[2 * N_NODES * NBLK];
  __shared__ float gihl[N_NODES * 12];
  __shared__ float shh [N_NODES * 12];
  __shared__ float gBl [N_NODES * 12];
  __shared__ float svals[128];
  __shared__ float sbi[384], sbh[384];
  __shared__ float sg[128], sbt[128];
  __shared__ float smean[32], srstd[32], sicnt[32];
  __shared__ int   snt[32], str[32], shF[192];
  __shared__ float pooled[256];
  __shared__ float red[4];

  // ---- this thread's weight row -> registers (24 distinct rows per block) --
  const float* wrow = (g < 3) ? (p.w_ih + (g * DIM + d) * DIM)
                              : (p.w_hh + ((g - 3) * DIM + d) * DIM);
  const float4* w4 = (const float4*)wrow;
  float4 wreg[32];
#pragma unroll
  for (int k = 0; k < 32; ++k) wreg[k] = w4[k];

  // ---- stage small tables ---------------------------------------------------
  if (t < 32)               { snt[t] = p.nt[t]; str[t] = p.tr[t]; }
  if (t < 384)              sbi[t] = p.b_ih[t];
  else                      sbh[t - 384] = p.b_hh[t - 384];
  if (t < 128)              sg[t]  = p.ln_g[t];
  else if (t < 256)         sbt[t - 128] = p.ln_b[t - 128];
  if (t < 192)              shF[t] = p.hF[t];
  for (int i = t; i < 1024; i += NTHR_G) {
    int s = i >> 5, n = i & 31;
    sAT[i] = (float)p.hA[n * 32 + s];
  }
  __syncthreads();

  // h0 (identical in every block) + B + 1/cnt
  for (int i = t; i < N_NODES * DIM; i += NTHR_G) {
    int n = i >> 7, dd = i & 127;
    sh[n][dd] = p.ne_w[snt[n] * DIM + dd] + p.te_w[str[n] * DIM + dd];
    float acc = 0.f;
#pragma unroll
    for (int f = 0; f < 6; ++f)
      acc = fmaf((float)shF[n * 6 + f], p.ef_w[f * DIM + dd], acc);
    sB[n][dd] = acc;
  }
  if (t < 32) {
    float c = 0.f;
    for (int s = 0; s < 32; ++s) c += sAT[s * 32 + t];
    sicnt[t] = 1.0f / fmaxf(c, 1.0f);
  }
  __syncthreads();

  // gB[n][ih-row] = B[n] . w_ih_row  (loop-invariant)
  if (g < 3) {
    const float4* x4 = (const float4*)&sB[u][0];
    float a0 = 0.f, a1 = 0.f, a2 = 0.f, a3 = 0.f;
#pragma unroll
    for (int k = 0; k < 32; k += 4) {
      float4 x0 = x4[k], x1 = x4[k+1], x2 = x4[k+2], x3 = x4[k+3];
      a0 = fmaf(wreg[k  ].x, x0.x, fmaf(wreg[k  ].y, x0.y, fmaf(wreg[k  ].z, x0.z, fmaf(wreg[k  ].w, x0.w, a0))));
      a1 = fmaf(wreg[k+1].x, x1.x, fmaf(wreg[k+1].y, x1.y, fmaf(wreg[k+1].z, x1.z, fmaf(wreg[k+1].w, x1.w, a1))));
      a2 = fmaf(wreg[k+2].x, x2.x, fmaf(wreg[k+2].y, x2.y, fmaf(wreg[k+2].z, x2.z, fmaf(wreg[k+2].w, x2.w, a2))));
      a3 = fmaf(wreg[k+3].x, x3.x, fmaf(wreg[k+3].y, x3.y, fmaf(wreg[k+3].z, x3.z, fmaf(wreg[k+3].w, x3.w, a3))));
    }
    gBl[u * 12 + dl * 3 + g] = (a0 + a1) + (a2 + a3);
  }
  __syncthreads();

  // ---- 5 GRU iterations -----------------------------------------------------
  for (int it = 0; it < 5; ++it) {
    float* hpb = (it & 1) ? p.hp1 : p.hp0;
    float* psb = (it & 1) ? p.ps1 : p.ps0;   // [ps 1024 | pq 1024]

    // 768 dots of len 128, weights in regs, x = sh[u]
    {
      const float4* x4 = (const float4*)&sh[u][0];
      float a0 = 0.f, a1 = 0.f, a2 = 0.f, a3 = 0.f;
#pragma unroll
      for (int k = 0; k < 32; k += 4) {
        float4 x0 = x4[k], x1 = x4[k+1], x2 = x4[k+2], x3 = x4[k+3];
        a0 = fmaf(wreg[k  ].x, x0.x, fmaf(wreg[k  ].y, x0.y, fmaf(wreg[k  ].z, x0.z, fmaf(wreg[k  ].w, x0.w, a0))));
        a1 = fmaf(wreg[k+1].x, x1.x, fmaf(wreg[k+1].y, x1.y, fmaf(wreg[k+1].z, x1.z, fmaf(wreg[k+1].w, x1.w, a1))));
        a2 = fmaf(wreg[k+2].x, x2.x, fmaf(wreg[k+2].y, x2.y, fmaf(wreg[k+2].z, x2.z, fmaf(wreg[k+2].w, x2.w, a2))));
        a3 = fmaf(wreg[k+3].x, x3.x, fmaf(wreg[k+3].y, x3.y, fmaf(wreg[k+3].z, x3.z, fmaf(wreg[k+3].w, x3.w, a3))));
      }
      float acc = (a0 + a1) + (a2 + a3);
      if (g < 3) gihl[u * 12 + dl * 3 + g] = acc;
      else       shh [u * 12 + dl * 3 + (g - 3)] = acc;
    }
    __syncthreads();

    // gates for this block's 4 dims x 32 nodes
    if (t < 128) {
      const int n = t >> 2, dli = t & 3, dd = b * 4 + dli;
      const float hprev = sh[n][dd];
      float gi0 = gBl[n * 12 + dli * 3 + 0];
      float gi1 = gBl[n * 12 + dli * 3 + 1];
      float gi2 = gBl[n * 12 + dli * 3 + 2];
      for (int s2 = 0; s2 < 32; ++s2) {
        const float a = sAT[s2 * 32 + n];
        gi0 = fmaf(a, gihl[s2 * 12 + dli * 3 + 0], gi0);
        gi1 = fmaf(a, gihl[s2 * 12 + dli * 3 + 1], gi1);
        gi2 = fmaf(a, gihl[s2 * 12 + dli * 3 + 2], gi2);
      }
      const float ic = sicnt[n];
      gi0 = gi0 * ic + sbi[dd];
      gi1 = gi1 * ic + sbi[128 + dd];
      gi2 = gi2 * ic + sbi[256 + dd];
      const float hr = shh[n * 12 + dli * 3 + 0] + sbh[dd];
      const float hz = shh[n * 12 + dli * 3 + 1] + sbh[128 + dd];
      const float hn = shh[n * 12 + dli * 3 + 2] + sbh[256 + dd];
      const float rr = 1.f / (1.f + expf(-(gi0 + hr)));
      const float zz = 1.f / (1.f + expf(-(gi1 + hz)));
      const float nn = tanhf(gi2 + rr * hn);
      svals[t] = (1.f - zz) * nn + zz * hprev;
    }
    __syncthreads();

    // exchange: pre-LN fragments + (sum, sumsq) partials via sc1
    if (t < 128) {
      const int n = t >> 2, dli = t & 3, dd = b * 4 + dli;
      st_sc1(&hpb[n * 128 + dd], svals[t]);
    }
    if (t < 32) {
      const float v0 = svals[t * 4],     v1 = svals[t * 4 + 1];
      const float v2 = svals[t * 4 + 2], v3 = svals[t * 4 + 3];
      st_sc1(&psb[b * 32 + t],        (v0 + v1) + (v2 + v3));
      st_sc1(&psb[1024 + b * 32 + t], (v0 * v0 + v1 * v1) + (v2 * v2 + v3 * v3));
    }
    grid_barrier(p.bar);

    // read back (coalesced 8B sc1 loads into LDS)
    {
      const unsigned long long* hp8 = (const unsigned long long*)hpb;
      unsigned long long* dsth = (unsigned long long*)hps;
      for (int i = t; i < N_NODES * DIM / 2; i += NTHR_G) dsth[i] = ld8_sc1(hp8 + i);
      const unsigned long long* pp8 = (const unsigned long long*)psb;
      unsigned long long* dstp = (unsigned long long*)spart;
      for (int i = t; i < 1024; i += NTHR_G) dstp[i] = ld8_sc1(pp8 + i);
    }
    __syncthreads();

    // mean / rstd per node (every block recomputes; fixed order)
    if (t < 32) {
      float m = 0.f, q = 0.f;
      for (int blk = 0; blk < NBLK; ++blk) {
        m += spart[blk * 32 + t];
        q += spart[1024 + blk * 32 + t];
      }
      const float mean = m * (1.0f / DIM);
      const float var  = q * (1.0f / DIM) - mean * mean;
      smean[t] = mean;
      srstd[t] = rsqrtf(var + 1e-5f);
    }
    __syncthreads();

    // normalize into sh
    for (int i = t; i < N_NODES * DIM; i += NTHR_G) {
      int n = i >> 7, dd = i & 127;
      sh[n][dd] = (hps[i] - smean[n]) * srstd[n] * sg[dd] + sbt[dd];
    }
    __syncthreads();
  }

  // ---------------- head (block 0) -------------------------------------------
  if (b == 0) {
    if (t < DIM) {
      float s = 0.f, mx = -INFINITY;
#pragma unroll
      for (int n2 = 0; n2 < N_NODES; ++n2) {
        float v = sh[n2][t];
        s += v; mx = fmaxf(mx, v);
      }
      pooled[t]       = s * (1.0f / N_NODES);
      pooled[t + DIM] = mx;
    }
    __syncthreads();

    if (t < DIM) {
      const float4* w4f = (const float4*)(p.fc1_w + t * 2 * DIM);
      const float4* p4 = (const float4*)pooled;
      float acc = p.fc1_b[t];
#pragma unroll 8
      for (int k = 0; k < 2 * DIM / 4; ++k) {
        float4 wv = w4f[k]; float4 pv = p4[k];
        acc = fmaf(wv.x, pv.x, acc);
        acc = fmaf(wv.y, pv.y, acc);
        acc = fmaf(wv.z, pv.z, acc);
        acc = fmaf(wv.w, pv.w, acc);
      }
      svals[t] = acc;
    }
    __syncthreads();

    if (t < DIM) {
      float s = svals[t];
#pragma unroll
      for (int o = 32; o > 0; o >>= 1) s += __shfl_down(s, o, 64);
      if ((t & 63) == 0) red[t >> 6] = s;
    }
    __syncthreads();
    const float mean2 = (red[0] + red[1]) * (1.0f / DIM);
    if (t < DIM) {
      float dx = svals[t] - mean2;
      float s = dx * dx;
#pragma unroll
      for (int o = 32; o > 0; o >>= 1) s += __shfl_down(s, o, 64);
      if ((t & 63) == 0) red[2 + (t >> 6)] = s;
    }
    __syncthreads();
    const float var2  = (red[2] + red[3]) * (1.0f / DIM);
    const float rstd2 = rsqrtf(var2 + 1e-5f);
    __syncthreads();
    if (t < DIM) {
      float x = (svals[t] - mean2) * rstd2 * p.ln2_g[t] + p.ln2_b[t];
      x = fmaxf(x, 0.f);
      float s = x * p.fc2_w[t];
#pragma unroll
      for (int o = 32; o > 0; o >>= 1) s += __shfl_down(s, o, 64);
      if ((t & 63) == 0) red[t >> 6] = s;
    }
    __syncthreads();
    if (t == 0) p.out[0] = red[0] + red[1] + p.fc2_b[0];
  }
}

// ---------------------------------------------------------------------------
extern "C" void kernel_launch(void* const* d_in, const int* in_sizes, int n_in,
                              void* d_out, int out_size, void* d_ws, size_t ws_size,
                              hipStream_t stream)
{
  const int*   nt    = (const int*)d_in[0];
  const int*   tr    = (const int*)d_in[1];
  const int*   es    = (const int*)d_in[2];
  const int*   ed    = (const int*)d_in[3];
  const int*   ef    = (const int*)d_in[4];
  const float* ne_w  = (const float*)d_in[5];
  const float* te_w  = (const float*)d_in[6];
  const float* ef_w  = (const float*)d_in[7];
  const float* w_ih  = (const float*)d_in[8];
  const float* w_hh  = (const float*)d_in[9];
  const float* b_ih  = (const float*)d_in[10];
  const float* b_hh  = (const float*)d_in[11];
  const float* ln_g  = (const float*)d_in[12];
  const float* ln_b  = (const float*)d_in[13];
  const float* fc1_w = (const float*)d_in[14];
  const float* fc1_b = (const float*)d_in[15];
  const float* ln2_g = (const float*)d_in[16];
  const float* ln2_b = (const float*)d_in[17];
  const float* fc2_w = (const float*)d_in[18];
  const float* fc2_b = (const float*)d_in[19];

  const int E = in_sizes[2];

  // ws: hA[1024]@0 | hF[192]@4096 | bar[2]@4992 | hp0@8192 | hp1@24576
  //     | ps0+pq0@40960 (8KB) | ps1+pq1@49152 (8KB)
  int*   hA  = (int*)d_ws;
  int*   hF  = (int*)((char*)d_ws + 4096);
  int*   bar = (int*)((char*)d_ws + 4992);
  float* hp0 = (float*)((char*)d_ws + 8192);
  float* hp1 = (float*)((char*)d_ws + 24576);
  float* ps0 = (float*)((char*)d_ws + 40960);
  float* ps1 = (float*)((char*)d_ws + 49152);

  hipMemsetAsync(d_ws, 0, 5120, stream);

  hipLaunchKernelGGL(hist_kernel, dim3(HIST_BLOCKS), dim3(NTHR_H), 0, stream,
                     es, ed, ef, E, hA, hF);

  GnnParams prm;
  prm.nt = nt; prm.tr = tr;
  prm.ne_w = ne_w; prm.te_w = te_w; prm.ef_w = ef_w;
  prm.w_ih = w_ih; prm.w_hh = w_hh; prm.b_ih = b_ih; prm.b_hh = b_hh;
  prm.ln_g = ln_g; prm.ln_b = ln_b;
  prm.fc1_w = fc1_w; prm.fc1_b = fc1_b;
  prm.ln2_g = ln2_g; prm.ln2_b = ln2_b;
  prm.fc2_w = fc2_w; prm.fc2_b = fc2_b;
  prm.hA = hA; prm.hF = hF; prm.bar = bar;
  prm.hp0 = hp0; prm.hp1 = hp1; prm.ps0 = ps0; prm.ps1 = ps1;
  prm.out = (float*)d_out;

  void* args[] = { &prm };
  hipLaunchCooperativeKernel((const void*)gnn_kernel, dim3(NBLK), dim3(NTHR_G),
                             args, 0, stream);
}

// Round 7
// 83.694 us; speedup vs baseline: 1.5112x; 1.5112x over previous
//
#include <hip/hip_runtime.h>
#include <math.h>

#define N_NODES 32
#define DIM     128
#define NBLK    32
#define NTHR_G  768   // 32 (node/src) x 4 (dims) x 6 (gate rows)
#define NTHR_H  256
#define HIST_BLOCKS 128
#define SH_PAD  132   // padded row stride (floats): bank-group spread for b128
#define SW_PAD  132

struct GnnParams {
  const int* nt; const int* tr;
  const float* ne_w; const float* te_w; const float* ef_w;
  const float* w_ih; const float* w_hh; const float* b_ih; const float* b_hh;
  const float* ln_g; const float* ln_b;
  const float* fc1_w; const float* fc1_b;
  const float* ln2_g; const float* ln2_b;
  const float* fc2_w; const float* fc2_b;
  const int* hA; const int* hF;
  int* bar;
  float* hp0; float* hp1;   // pre-LN h exchange (ping-pong) [32*128]
  float* ps0; float* ps1;   // partials: [ps(1024) | pq(1024)] contiguous each
  float* out;
};

// ---- lightweight grid barrier: NO threadfence (no L2 invalidation) ---------
__device__ __forceinline__ void grid_barrier(int* bar) {
  asm volatile("s_waitcnt vmcnt(0)" ::: "memory");  // drain sc1 stores
  __syncthreads();
  if (threadIdx.x == 0) {
    int gen = __hip_atomic_load(&bar[1], __ATOMIC_RELAXED, __HIP_MEMORY_SCOPE_AGENT);
    int arrived = __hip_atomic_fetch_add(&bar[0], 1, __ATOMIC_RELAXED,
                                         __HIP_MEMORY_SCOPE_AGENT);
    if (arrived == NBLK - 1) {
      __hip_atomic_store(&bar[0], 0, __ATOMIC_RELAXED, __HIP_MEMORY_SCOPE_AGENT);
      __hip_atomic_fetch_add(&bar[1], 1, __ATOMIC_RELEASE, __HIP_MEMORY_SCOPE_AGENT);
    } else {
      while (__hip_atomic_load(&bar[1], __ATOMIC_RELAXED,
                               __HIP_MEMORY_SCOPE_AGENT) == gen)
        __builtin_amdgcn_s_sleep(1);
    }
  }
  __syncthreads();
}

__device__ __forceinline__ void st_sc1(float* p, float v) {
  __hip_atomic_store(p, v, __ATOMIC_RELAXED, __HIP_MEMORY_SCOPE_AGENT);
}
__device__ __forceinline__ unsigned long long ld8_sc1(const unsigned long long* p) {
  return __hip_atomic_load(p, __ATOMIC_RELAXED, __HIP_MEMORY_SCOPE_AGENT);
}

// ---------------- histogram over edges (index-only, loop-invariant) ---------
__global__ __launch_bounds__(NTHR_H) void hist_kernel(
    const int* __restrict__ es, const int* __restrict__ ed,
    const int* __restrict__ ef, int E,
    int* __restrict__ hA, int* __restrict__ hF)
{
  __shared__ int lA[N_NODES * N_NODES];
  __shared__ int lF[N_NODES * 6];
  const int t = threadIdx.x;
  for (int i = t; i < N_NODES * N_NODES; i += NTHR_H) lA[i] = 0;
  for (int i = t; i < N_NODES * 6;       i += NTHR_H) lF[i] = 0;
  __syncthreads();

  const int E4 = E >> 2;
  const int4* es4 = (const int4*)es;
  const int4* ed4 = (const int4*)ed;
  const int4* ef4 = (const int4*)ef;
  #define DO_EDGE(S, D, F) \
    if ((unsigned)(S) < N_NODES && (unsigned)(D) < N_NODES) { \
      atomicAdd(&lA[(D) * N_NODES + (S)], 1); \
      atomicAdd(&lF[(D) * 6 + (F)], 1); }
  for (int i = blockIdx.x * NTHR_H + t; i < E4; i += gridDim.x * NTHR_H) {
    int4 s4 = es4[i], d4 = ed4[i], f4 = ef4[i];
    DO_EDGE(s4.x, d4.x, f4.x)
    DO_EDGE(s4.y, d4.y, f4.y)
    DO_EDGE(s4.z, d4.z, f4.z)
    DO_EDGE(s4.w, d4.w, f4.w)
  }
  if (blockIdx.x == 0) {
    for (int e = (E4 << 2) + t; e < E; e += NTHR_H) {
      int s = es[e], d = ed[e], f = ef[e];
      DO_EDGE(s, d, f)
    }
  }
  #undef DO_EDGE
  __syncthreads();
  for (int i = t; i < N_NODES * N_NODES; i += NTHR_H) { int v = lA[i]; if (v) atomicAdd(&hA[i], v); }
  for (int i = t; i < N_NODES * 6;       i += NTHR_H) { int v = lF[i]; if (v) atomicAdd(&hF[i], v); }
}

// --------- GRU kernel: block owns 4 output dims; weights live in LDS --------
__global__ __launch_bounds__(NTHR_G) void gnn_kernel(GnnParams p)
{
  const int b = blockIdx.x;          // owns dims [4b, 4b+4)
  const int t = threadIdx.x;
  const int u  = t / 24;             // node (hh dots) or src (gih dots), 0..31
  const int r  = t - u * 24;         // local row 0..23  (r = dl*6 + g)
  const int dl = r / 6;              // local dim 0..3
  const int g  = r - dl * 6;         // gate row: 0..2 = ih(r,z,n), 3..5 = hh

  __shared__ float sW[24][SW_PAD];          // this block's 24 weight rows (12.7 KB)
  __shared__ float sh[N_NODES][SH_PAD];     // post-LN h (padded rows)
  __shared__ float sB[N_NODES][DIM];        // B = F @ ef_w (loop-invariant)
  __shared__ float hps[N_NODES * DIM];      // staged pre-LN h
  __shared__ float sAT[N_NODES * N_NODES];  // A transposed: sAT[s*32+n]
  __shared__ float spart[2 * N_NODES * NBLK];
  __shared__ float gihl[N_NODES * 12];
  __shared__ float shh [N_NODES * 12];
  __shared__ float gBl [N_NODES * 12];
  __shared__ float svals[128];
  __shared__ float sbi[384], sbh[384];
  __shared__ float sg[128], sbt[128];
  __shared__ float smean[32], srstd[32], sicnt[32];
  __shared__ int   snt[32], str[32], shF[192];
  __shared__ float pooled[256];
  __shared__ float red[4];

  // ---- load this block's 24 weight rows into LDS (one float4 per thread) ---
  {
    const int rowi = t >> 5;           // 0..23
    const int k4   = t & 31;           // float4 index within row
    const int gg   = rowi % 6;
    const int ddl  = rowi / 6;
    const int dglob = b * 4 + ddl;
    const float* wr = (gg < 3) ? (p.w_ih + (gg * DIM + dglob) * DIM)
                               : (p.w_hh + ((gg - 3) * DIM + dglob) * DIM);
    *(float4*)&sW[rowi][k4 * 4] = *(const float4*)(wr + k4 * 4);
  }

  // ---- stage small tables ---------------------------------------------------
  if (t < 32)               { snt[t] = p.nt[t]; str[t] = p.tr[t]; }
  if (t < 384)              sbi[t] = p.b_ih[t];
  else                      sbh[t - 384] = p.b_hh[t - 384];
  if (t < 128)              sg[t]  = p.ln_g[t];
  else if (t < 256)         sbt[t - 128] = p.ln_b[t - 128];
  if (t < 192)              shF[t] = p.hF[t];
  for (int i = t; i < 1024; i += NTHR_G) {
    int s = i >> 5, n = i & 31;
    sAT[i] = (float)p.hA[n * 32 + s];
  }
  __syncthreads();

  // h0 (identical in every block) + B + 1/cnt
  for (int i = t; i < N_NODES * DIM; i += NTHR_G) {
    int n = i >> 7, dd = i & 127;
    sh[n][dd] = p.ne_w[snt[n] * DIM + dd] + p.te_w[str[n] * DIM + dd];
    float acc = 0.f;
#pragma unroll
    for (int f = 0; f < 6; ++f)
      acc = fmaf((float)shF[n * 6 + f], p.ef_w[f * DIM + dd], acc);
    sB[n][dd] = acc;
  }
  if (t < 32) {
    float c = 0.f;
    for (int s = 0; s < 32; ++s) c += sAT[s * 32 + t];
    sicnt[t] = 1.0f / fmaxf(c, 1.0f);
  }
  __syncthreads();

  // gB[n][ih-row] = B[n] . w_ih_row  (loop-invariant)
  if (g < 3) {
    const float4* x4 = (const float4*)&sB[u][0];
    const float4* w4 = (const float4*)&sW[r][0];
    float a0 = 0.f, a1 = 0.f, a2 = 0.f, a3 = 0.f;
#pragma unroll
    for (int k = 0; k < 32; k += 4) {
      float4 w0 = w4[k], w1 = w4[k+1], w2 = w4[k+2], w3 = w4[k+3];
      float4 x0 = x4[k], x1 = x4[k+1], x2 = x4[k+2], x3 = x4[k+3];
      a0 = fmaf(w0.x, x0.x, fmaf(w0.y, x0.y, fmaf(w0.z, x0.z, fmaf(w0.w, x0.w, a0))));
      a1 = fmaf(w1.x, x1.x, fmaf(w1.y, x1.y, fmaf(w1.z, x1.z, fmaf(w1.w, x1.w, a1))));
      a2 = fmaf(w2.x, x2.x, fmaf(w2.y, x2.y, fmaf(w2.z, x2.z, fmaf(w2.w, x2.w, a2))));
      a3 = fmaf(w3.x, x3.x, fmaf(w3.y, x3.y, fmaf(w3.z, x3.z, fmaf(w3.w, x3.w, a3))));
    }
    gBl[u * 12 + dl * 3 + g] = (a0 + a1) + (a2 + a3);
  }
  __syncthreads();

  // ---- 5 GRU iterations -----------------------------------------------------
  for (int it = 0; it < 5; ++it) {
    float* hpb = (it & 1) ? p.hp1 : p.hp0;
    float* psb = (it & 1) ? p.ps1 : p.ps0;   // [ps 1024 | pq 1024]

    // 768 dots of len 128: weights from LDS (broadcast across u), x = sh[u]
    {
      const float4* x4 = (const float4*)&sh[u][0];
      const float4* w4 = (const float4*)&sW[r][0];
      float a0 = 0.f, a1 = 0.f, a2 = 0.f, a3 = 0.f;
#pragma unroll
      for (int k = 0; k < 32; k += 4) {
        float4 w0 = w4[k], w1 = w4[k+1], w2 = w4[k+2], w3 = w4[k+3];
        float4 x0 = x4[k], x1 = x4[k+1], x2 = x4[k+2], x3 = x4[k+3];
        a0 = fmaf(w0.x, x0.x, fmaf(w0.y, x0.y, fmaf(w0.z, x0.z, fmaf(w0.w, x0.w, a0))));
        a1 = fmaf(w1.x, x1.x, fmaf(w1.y, x1.y, fmaf(w1.z, x1.z, fmaf(w1.w, x1.w, a1))));
        a2 = fmaf(w2.x, x2.x, fmaf(w2.y, x2.y, fmaf(w2.z, x2.z, fmaf(w2.w, x2.w, a2))));
        a3 = fmaf(w3.x, x3.x, fmaf(w3.y, x3.y, fmaf(w3.z, x3.z, fmaf(w3.w, x3.w, a3))));
      }
      float acc = (a0 + a1) + (a2 + a3);
      if (g < 3) gihl[u * 12 + dl * 3 + g] = acc;
      else       shh [u * 12 + dl * 3 + (g - 3)] = acc;
    }
    __syncthreads();

    // gates for this block's 4 dims x 32 nodes
    if (t < 128) {
      const int n = t >> 2, dli = t & 3, dd = b * 4 + dli;
      const float hprev = sh[n][dd];
      float gi0 = gBl[n * 12 + dli * 3 + 0];
      float gi1 = gBl[n * 12 + dli * 3 + 1];
      float gi2 = gBl[n * 12 + dli * 3 + 2];
      for (int s2 = 0; s2 < 32; ++s2) {
        const float a = sAT[s2 * 32 + n];
        gi0 = fmaf(a, gihl[s2 * 12 + dli * 3 + 0], gi0);
        gi1 = fmaf(a, gihl[s2 * 12 + dli * 3 + 1], gi1);
        gi2 = fmaf(a, gihl[s2 * 12 + dli * 3 + 2], gi2);
      }
      const float ic = sicnt[n];
      gi0 = gi0 * ic + sbi[dd];
      gi1 = gi1 * ic + sbi[128 + dd];
      gi2 = gi2 * ic + sbi[256 + dd];
      const float hr = shh[n * 12 + dli * 3 + 0] + sbh[dd];
      const float hz = shh[n * 12 + dli * 3 + 1] + sbh[128 + dd];
      const float hn = shh[n * 12 + dli * 3 + 2] + sbh[256 + dd];
      const float rr = 1.f / (1.f + expf(-(gi0 + hr)));
      const float zz = 1.f / (1.f + expf(-(gi1 + hz)));
      const float nn = tanhf(gi2 + rr * hn);
      svals[t] = (1.f - zz) * nn + zz * hprev;
    }
    __syncthreads();

    // exchange: pre-LN fragments + (sum, sumsq) partials via sc1
    if (t < 128) {
      const int n = t >> 2, dli = t & 3, dd = b * 4 + dli;
      st_sc1(&hpb[n * 128 + dd], svals[t]);
    }
    if (t < 32) {
      const float v0 = svals[t * 4],     v1 = svals[t * 4 + 1];
      const float v2 = svals[t * 4 + 2], v3 = svals[t * 4 + 3];
      st_sc1(&psb[b * 32 + t],        (v0 + v1) + (v2 + v3));
      st_sc1(&psb[1024 + b * 32 + t], (v0 * v0 + v1 * v1) + (v2 * v2 + v3 * v3));
    }
    grid_barrier(p.bar);

    // read back (coalesced 8B sc1 loads into LDS)
    {
      const unsigned long long* hp8 = (const unsigned long long*)hpb;
      unsigned long long* dsth = (unsigned long long*)hps;
      for (int i = t; i < N_NODES * DIM / 2; i += NTHR_G) dsth[i] = ld8_sc1(hp8 + i);
      const unsigned long long* pp8 = (const unsigned long long*)psb;
      unsigned long long* dstp = (unsigned long long*)spart;
      for (int i = t; i < 1024; i += NTHR_G) dstp[i] = ld8_sc1(pp8 + i);
    }
    __syncthreads();

    // mean / rstd per node (every block recomputes; fixed order)
    if (t < 32) {
      float m = 0.f, q = 0.f;
      for (int blk = 0; blk < NBLK; ++blk) {
        m += spart[blk * 32 + t];
        q += spart[1024 + blk * 32 + t];
      }
      const float mean = m * (1.0f / DIM);
      const float var  = q * (1.0f / DIM) - mean * mean;
      smean[t] = mean;
      srstd[t] = rsqrtf(var + 1e-5f);
    }
    __syncthreads();

    // normalize into sh
    for (int i = t; i < N_NODES * DIM; i += NTHR_G) {
      int n = i >> 7, dd = i & 127;
      sh[n][dd] = (hps[i] - smean[n]) * srstd[n] * sg[dd] + sbt[dd];
    }
    __syncthreads();
  }

  // ---------------- head (block 0) -------------------------------------------
  if (b == 0) {
    if (t < DIM) {
      float s = 0.f, mx = -INFINITY;
#pragma unroll
      for (int n2 = 0; n2 < N_NODES; ++n2) {
        float v = sh[n2][t];
        s += v; mx = fmaxf(mx, v);
      }
      pooled[t]       = s * (1.0f / N_NODES);
      pooled[t + DIM] = mx;
    }
    __syncthreads();

    if (t < DIM) {
      const float4* w4f = (const float4*)(p.fc1_w + t * 2 * DIM);
      const float4* p4 = (const float4*)pooled;
      float acc = p.fc1_b[t];
#pragma unroll 8
      for (int k = 0; k < 2 * DIM / 4; ++k) {
        float4 wv = w4f[k]; float4 pv = p4[k];
        acc = fmaf(wv.x, pv.x, acc);
        acc = fmaf(wv.y, pv.y, acc);
        acc = fmaf(wv.z, pv.z, acc);
        acc = fmaf(wv.w, pv.w, acc);
      }
      svals[t] = acc;
    }
    __syncthreads();

    if (t < DIM) {
      float s = svals[t];
#pragma unroll
      for (int o = 32; o > 0; o >>= 1) s += __shfl_down(s, o, 64);
      if ((t & 63) == 0) red[t >> 6] = s;
    }
    __syncthreads();
    const float mean2 = (red[0] + red[1]) * (1.0f / DIM);
    if (t < DIM) {
      float dx = svals[t] - mean2;
      float s = dx * dx;
#pragma unroll
      for (int o = 32; o > 0; o >>= 1) s += __shfl_down(s, o, 64);
      if ((t & 63) == 0) red[2 + (t >> 6)] = s;
    }
    __syncthreads();
    const float var2  = (red[2] + red[3]) * (1.0f / DIM);
    const float rstd2 = rsqrtf(var2 + 1e-5f);
    __syncthreads();
    if (t < DIM) {
      float x = (svals[t] - mean2) * rstd2 * p.ln2_g[t] + p.ln2_b[t];
      x = fmaxf(x, 0.f);
      float s = x * p.fc2_w[t];
#pragma unroll
      for (int o = 32; o > 0; o >>= 1) s += __shfl_down(s, o, 64);
      if ((t & 63) == 0) red[t >> 6] = s;
    }
    __syncthreads();
    if (t == 0) p.out[0] = red[0] + red[1] + p.fc2_b[0];
  }
}

// ---------------------------------------------------------------------------
extern "C" void kernel_launch(void* const* d_in, const int* in_sizes, int n_in,
                              void* d_out, int out_size, void* d_ws, size_t ws_size,
                              hipStream_t stream)
{
  const int*   nt    = (const int*)d_in[0];
  const int*   tr    = (const int*)d_in[1];
  const int*   es    = (const int*)d_in[2];
  const int*   ed    = (const int*)d_in[3];
  const int*   ef    = (const int*)d_in[4];
  const float* ne_w  = (const float*)d_in[5];
  const float* te_w  = (const float*)d_in[6];
  const float* ef_w  = (const float*)d_in[7];
  const float* w_ih  = (const float*)d_in[8];
  const float* w_hh  = (const float*)d_in[9];
  const float* b_ih  = (const float*)d_in[10];
  const float* b_hh  = (const float*)d_in[11];
  const float* ln_g  = (const float*)d_in[12];
  const float* ln_b  = (const float*)d_in[13];
  const float* fc1_w = (const float*)d_in[14];
  const float* fc1_b = (const float*)d_in[15];
  const float* ln2_g = (const float*)d_in[16];
  const float* ln2_b = (const float*)d_in[17];
  const float* fc2_w = (const float*)d_in[18];
  const float* fc2_b = (const float*)d_in[19];

  const int E = in_sizes[2];

  // ws: hA[1024]@0 | hF[192]@4096 | bar[2]@4992 | hp0@8192 | hp1@24576
  //     | ps0+pq0@40960 (8KB) | ps1+pq1@49152 (8KB)
  int*   hA  = (int*)d_ws;
  int*   hF  = (int*)((char*)d_ws + 4096);
  int*   bar = (int*)((char*)d_ws + 4992);
  float* hp0 = (float*)((char*)d_ws + 8192);
  float* hp1 = (float*)((char*)d_ws + 24576);
  float* ps0 = (float*)((char*)d_ws + 40960);
  float* ps1 = (float*)((char*)d_ws + 49152);

  hipMemsetAsync(d_ws, 0, 5120, stream);

  hipLaunchKernelGGL(hist_kernel, dim3(HIST_BLOCKS), dim3(NTHR_H), 0, stream,
                     es, ed, ef, E, hA, hF);

  GnnParams prm;
  prm.nt = nt; prm.tr = tr;
  prm.ne_w = ne_w; prm.te_w = te_w; prm.ef_w = ef_w;
  prm.w_ih = w_ih; prm.w_hh = w_hh; prm.b_ih = b_ih; prm.b_hh = b_hh;
  prm.ln_g = ln_g; prm.ln_b = ln_b;
  prm.fc1_w = fc1_w; prm.fc1_b = fc1_b;
  prm.ln2_g = ln2_g; prm.ln2_b = ln2_b;
  prm.fc2_w = fc2_w; prm.fc2_b = fc2_b;
  prm.hA = hA; prm.hF = hF; prm.bar = bar;
  prm.hp0 = hp0; prm.hp1 = hp1; prm.ps0 = ps0; prm.ps1 = ps1;
  prm.out = (float*)d_out;

  void* args[] = { &prm };
  hipLaunchCooperativeKernel((const void*)gnn_kernel, dim3(NBLK), dim3(NTHR_G),
                             args, 0, stream);
}

// Round 8
// 54.689 us; speedup vs baseline: 2.3127x; 1.5304x over previous
//
#include <hip/hip_runtime.h>
#include <math.h>

#define N_NODES 32
#define DIM     128
#define NTHR_H  256
#define HIST_BLOCKS 64
#define NTHR_P  256
#define PACK_BLOCKS 48
#define NTHR_G  512   // 8 waves, single workgroup

typedef __attribute__((ext_vector_type(8))) short bf16x8;
typedef __attribute__((ext_vector_type(4))) float f32x4;

// round-to-nearest-even f32 -> bf16 bits (finite values only)
__device__ __forceinline__ unsigned short f2bf(float f) {
  unsigned int u = __float_as_uint(f);
  u += 0x7fffu + ((u >> 16) & 1u);
  return (unsigned short)(u >> 16);
}

__device__ __forceinline__ float sigm(float x) { return 1.f / (1.f + expf(-x)); }

// ---------------- histogram over edges (index-only, loop-invariant) ---------
__global__ __launch_bounds__(NTHR_H) void hist_kernel(
    const int* __restrict__ es, const int* __restrict__ ed,
    const int* __restrict__ ef, int E,
    int* __restrict__ hA, int* __restrict__ hF)
{
  __shared__ int lA[N_NODES * N_NODES];
  __shared__ int lF[N_NODES * 6];
  const int t = threadIdx.x;
  for (int i = t; i < N_NODES * N_NODES; i += NTHR_H) lA[i] = 0;
  for (int i = t; i < N_NODES * 6;       i += NTHR_H) lF[i] = 0;
  __syncthreads();

  const int E4 = E >> 2;
  const int4* es4 = (const int4*)es;
  const int4* ed4 = (const int4*)ed;
  const int4* ef4 = (const int4*)ef;
  #define DO_EDGE(S, D, F) \
    if ((unsigned)(S) < N_NODES && (unsigned)(D) < N_NODES) { \
      atomicAdd(&lA[(D) * N_NODES + (S)], 1); \
      atomicAdd(&lF[(D) * 6 + (F)], 1); }
  for (int i = blockIdx.x * NTHR_H + t; i < E4; i += gridDim.x * NTHR_H) {
    int4 s4 = es4[i], d4 = ed4[i], f4 = ef4[i];
    DO_EDGE(s4.x, d4.x, f4.x)
    DO_EDGE(s4.y, d4.y, f4.y)
    DO_EDGE(s4.z, d4.z, f4.z)
    DO_EDGE(s4.w, d4.w, f4.w)
  }
  if (blockIdx.x == 0) {
    for (int e = (E4 << 2) + t; e < E; e += NTHR_H) {
      int s = es[e], d = ed[e], f = ef[e];
      DO_EDGE(s, d, f)
    }
  }
  #undef DO_EDGE
  __syncthreads();
  for (int i = t; i < N_NODES * N_NODES; i += NTHR_H) { int v = lA[i]; if (v) atomicAdd(&hA[i], v); }
  for (int i = t; i < N_NODES * 6;       i += NTHR_H) { int v = lF[i]; if (v) atomicAdd(&hF[i], v); }
}

// ------- pack [w_ih;w_hh] (768x128 fp32) into bf16 B-fragments --------------
// B-frag for mfma_f32_16x16x32_bf16: lane l holds B[k][n] with n = l&15,
// k = (l>>4)*8 + j (8 contiguous k). Tile T = mm*96 + nt*4 + kt.
__global__ __launch_bounds__(NTHR_P) void pack_kernel(
    const float* __restrict__ w_ih, const float* __restrict__ w_hh,
    unsigned short* __restrict__ pack)
{
  const int gid = blockIdx.x * NTHR_P + threadIdx.x;  // 0..12287
  const int T = gid >> 6;          // 0..191
  const int l = gid & 63;
  const int mm = T / 96;           // 0 = w_ih, 1 = w_hh
  const int t2 = T % 96;
  const int nt = t2 >> 2;          // 0..23 row-tile over 384
  const int kt = t2 & 3;
  const int row = nt * 16 + (l & 15);
  const int k   = kt * 32 + (l >> 4) * 8;
  const float* src = (mm ? w_hh : w_ih) + row * DIM + k;
  bf16x8 out;
#pragma unroll
  for (int j = 0; j < 8; ++j) out[j] = (short)f2bf(src[j]);
  *(bf16x8*)(pack + (size_t)T * 512 + l * 8) = out;
}

// --------- single-workgroup GRU: MFMA matmuls, gates/LN in registers --------
struct GnnParams {
  const int* nt; const int* tr;
  const float* ne_w; const float* te_w; const float* ef_w;
  const float* b_ih; const float* b_hh;
  const float* ln_g; const float* ln_b;
  const float* fc1_w; const float* fc1_b;
  const float* ln2_g; const float* ln2_b;
  const float* fc2_w; const float* fc2_b;
  const int* hA; const int* hF;
  const unsigned short* pack;
  float* out;
};

#define SHS 132   // fp32 row stride (elements)
#define SBS 136   // bf16 row stride (elements, 272 B: 16B-aligned, 2-way banks)
#define STS 40    // bf16 transposed stride (80 B)

__global__ __launch_bounds__(NTHR_G) void gnn_kernel(GnnParams p)
{
  const int t = threadIdx.x;
  const int w = t >> 6;           // wave 0..7  (= dim-tile nb)
  const int l = t & 63;
  const int g = l >> 4;           // 0..3
  const int ln16 = l & 15;
  const int nb = w;

  __shared__ float sh[N_NODES * SHS];                 // fp32 post-LN h
  __shared__ float sBnorm[N_NODES * SHS];             // (F@ef_w)/cnt
  __shared__ __align__(16) unsigned short hbf [N_NODES * SBS];  // bf16 h (row-major)
  __shared__ __align__(16) unsigned short hagg[N_NODES * SBS];  // bf16 agg
  __shared__ __align__(16) unsigned short hbT [DIM * STS];      // bf16 h^T [dim][src]
  __shared__ __align__(16) unsigned short anormP[2 * 64 * 8];   // A-frags of A/cnt
  __shared__ float part_s[N_NODES * 8], part_q[N_NODES * 8];
  __shared__ float sbi[384], sbh[384], sg[DIM], sbt[DIM];
  __shared__ float sicnt[N_NODES], smean[N_NODES], srstd[N_NODES];
  __shared__ int   shF[192], snt[N_NODES], str[N_NODES];
  __shared__ float pooled[2 * DIM], svals[DIM], red[4];

  // ---------------- init ----------------------------------------------------
  if (t < 32) { snt[t] = p.nt[t]; str[t] = p.tr[t]; }
  for (int i = t; i < 768; i += NTHR_G) {
    if (i < 384) sbi[i] = p.b_ih[i]; else sbh[i - 384] = p.b_hh[i - 384];
  }
  if (t < DIM) { sg[t] = p.ln_g[t]; sbt[t] = p.ln_b[t]; }
  if (t < 192) shF[t] = p.hF[t];
  if (t < 32) {
    int c = 0;
    for (int s = 0; s < 32; ++s) c += p.hA[t * 32 + s];
    sicnt[t] = 1.0f / fmaxf((float)c, 1.0f);
  }
  __syncthreads();

  for (int i = t; i < N_NODES * DIM; i += NTHR_G) {
    const int n = i >> 7, dd = i & (DIM - 1);
    const float v = p.ne_w[snt[n] * DIM + dd] + p.te_w[str[n] * DIM + dd];
    sh[n * SHS + dd] = v;
    const unsigned short bv = f2bf(v);
    hbf[n * SBS + dd] = bv;
    hbT[dd * STS + n] = bv;
    float acc = 0.f;
#pragma unroll
    for (int f = 0; f < 6; ++f)
      acc = fmaf((float)shF[n * 6 + f], p.ef_w[f * DIM + dd], acc);
    sBnorm[n * SHS + dd] = acc * sicnt[n];
  }
  if (t < 128) {                      // pack Anorm A-fragments (2 m-tiles)
    const int mt = t >> 6, ll = t & 63;
    const int m = mt * 16 + (ll & 15);
    const float ic = sicnt[m];
#pragma unroll
    for (int j = 0; j < 8; ++j) {
      const int s = (ll >> 4) * 8 + j;
      anormP[(mt * 64 + ll) * 8 + j] = f2bf((float)p.hA[m * 32 + s] * ic);
    }
  }
  __syncthreads();

  const unsigned short* packB = p.pack;
  const int dd = nb * 16 + ln16;               // this lane's dim
  const float bi0 = sbi[dd], bi1 = sbi[128 + dd], bi2 = sbi[256 + dd];
  const float bh0 = sbh[dd], bh1 = sbh[128 + dd], bh2 = sbh[256 + dd];
  const f32x4 fz = {0.f, 0.f, 0.f, 0.f};

  // ---------------- 5 GRU iterations ----------------------------------------
  for (int it = 0; it < 5; ++it) {
    // Phase A: agg = Anorm@H + Bnorm  (16 tiles, 2 per wave; K=32 = one MFMA)
    {
      const bf16x8 a0 = *(const bf16x8*)&anormP[(0 * 64 + l) * 8];
      const bf16x8 a1 = *(const bf16x8*)&anormP[(1 * 64 + l) * 8];
      const bf16x8 bT = *(const bf16x8*)&hbT[dd * STS + g * 8];
      f32x4 c0, c1;
#pragma unroll
      for (int j = 0; j < 4; ++j) {
        c0[j] = sBnorm[(g * 4 + j) * SHS + dd];
        c1[j] = sBnorm[(16 + g * 4 + j) * SHS + dd];
      }
      const f32x4 d0 = __builtin_amdgcn_mfma_f32_16x16x32_bf16(a0, bT, c0, 0, 0, 0);
      const f32x4 d1 = __builtin_amdgcn_mfma_f32_16x16x32_bf16(a1, bT, c1, 0, 0, 0);
#pragma unroll
      for (int j = 0; j < 4; ++j) {
        hagg[(g * 4 + j) * SBS + dd]      = f2bf(d0[j]);
        hagg[(16 + g * 4 + j) * SBS + dd] = f2bf(d1[j]);
      }
    }
    __syncthreads();

    // Phase B: C_ih = agg@w_ih^T, C_hh = h@w_hh^T  (12 D-tiles per wave)
    f32x4 A00 = fz, A01 = fz, A02 = fz, A10 = fz, A11 = fz, A12 = fz;
    f32x4 H00 = fz, H01 = fz, H02 = fz, H10 = fz, H11 = fz, H12 = fz;
#pragma unroll
    for (int kt = 0; kt < 4; ++kt) {
      const size_t lb = (size_t)l * 8;
      const bf16x8 b0 = *(const bf16x8*)(packB + ((size_t)((0 * 8 + nb) * 4 + kt)) * 512 + lb);
      const bf16x8 b1 = *(const bf16x8*)(packB + ((size_t)((1 * 8 + nb) * 4 + kt)) * 512 + lb);
      const bf16x8 b2 = *(const bf16x8*)(packB + ((size_t)((2 * 8 + nb) * 4 + kt)) * 512 + lb);
      const bf16x8 e0 = *(const bf16x8*)(packB + ((size_t)(96 + (0 * 8 + nb) * 4 + kt)) * 512 + lb);
      const bf16x8 e1 = *(const bf16x8*)(packB + ((size_t)(96 + (1 * 8 + nb) * 4 + kt)) * 512 + lb);
      const bf16x8 e2 = *(const bf16x8*)(packB + ((size_t)(96 + (2 * 8 + nb) * 4 + kt)) * 512 + lb);
      const int ko = kt * 32 + g * 8;
      const bf16x8 ai0 = *(const bf16x8*)&hagg[(ln16)      * SBS + ko];
      const bf16x8 ai1 = *(const bf16x8*)&hagg[(16 + ln16) * SBS + ko];
      const bf16x8 ah0 = *(const bf16x8*)&hbf [(ln16)      * SBS + ko];
      const bf16x8 ah1 = *(const bf16x8*)&hbf [(16 + ln16) * SBS + ko];
      A00 = __builtin_amdgcn_mfma_f32_16x16x32_bf16(ai0, b0, A00, 0, 0, 0);
      A01 = __builtin_amdgcn_mfma_f32_16x16x32_bf16(ai0, b1, A01, 0, 0, 0);
      A02 = __builtin_amdgcn_mfma_f32_16x16x32_bf16(ai0, b2, A02, 0, 0, 0);
      A10 = __builtin_amdgcn_mfma_f32_16x16x32_bf16(ai1, b0, A10, 0, 0, 0);
      A11 = __builtin_amdgcn_mfma_f32_16x16x32_bf16(ai1, b1, A11, 0, 0, 0);
      A12 = __builtin_amdgcn_mfma_f32_16x16x32_bf16(ai1, b2, A12, 0, 0, 0);
      H00 = __builtin_amdgcn_mfma_f32_16x16x32_bf16(ah0, e0, H00, 0, 0, 0);
      H01 = __builtin_amdgcn_mfma_f32_16x16x32_bf16(ah0, e1, H01, 0, 0, 0);
      H02 = __builtin_amdgcn_mfma_f32_16x16x32_bf16(ah0, e2, H02, 0, 0, 0);
      H10 = __builtin_amdgcn_mfma_f32_16x16x32_bf16(ah1, e0, H10, 0, 0, 0);
      H11 = __builtin_amdgcn_mfma_f32_16x16x32_bf16(ah1, e1, H11, 0, 0, 0);
      H12 = __builtin_amdgcn_mfma_f32_16x16x32_bf16(ah1, e2, H12, 0, 0, 0);
    }

    // Phase C: gates in registers; D-layout: n = l&15 (dim), m = g*4 + j (node)
    float hp00, hp01, hp02, hp03, hp10, hp11, hp12, hp13;
    #define GATE(J, AI0, AI1, AI2, HH0, HH1, HH2, MBASE, OUT)                  \
    {                                                                          \
      const int m_ = (MBASE) + g * 4 + (J);                                    \
      const float r_ = sigm(AI0[J] + bi0 + HH0[J] + bh0);                      \
      const float z_ = sigm(AI1[J] + bi1 + HH1[J] + bh1);                      \
      const float n_ = tanhf(AI2[J] + bi2 + r_ * (HH2[J] + bh2));              \
      const float hp_ = sh[m_ * SHS + dd];                                     \
      OUT = (1.f - z_) * n_ + z_ * hp_;                                        \
    }
    GATE(0, A00, A01, A02, H00, H01, H02, 0,  hp00)
    GATE(1, A00, A01, A02, H00, H01, H02, 0,  hp01)
    GATE(2, A00, A01, A02, H00, H01, H02, 0,  hp02)
    GATE(3, A00, A01, A02, H00, H01, H02, 0,  hp03)
    GATE(0, A10, A11, A12, H10, H11, H12, 16, hp10)
    GATE(1, A10, A11, A12, H10, H11, H12, 16, hp11)
    GATE(2, A10, A11, A12, H10, H11, H12, 16, hp12)
    GATE(3, A10, A11, A12, H10, H11, H12, 16, hp13)
    #undef GATE

    // LN partials: reduce over the 16 dim-lanes per (node) value
    #define RED16(V, MBASE, J)                                                 \
    {                                                                          \
      float s_ = (V), q_ = (V) * (V);                                          \
      _Pragma("unroll")                                                        \
      for (int mk = 1; mk < 16; mk <<= 1) {                                    \
        s_ += __shfl_xor(s_, mk, 16);                                          \
        q_ += __shfl_xor(q_, mk, 16);                                          \
      }                                                                        \
      if (ln16 == 0) {                                                         \
        const int m_ = (MBASE) + g * 4 + (J);                                  \
        part_s[m_ * 8 + nb] = s_;  part_q[m_ * 8 + nb] = q_;                   \
      }                                                                        \
    }
    RED16(hp00, 0, 0)  RED16(hp01, 0, 1)  RED16(hp02, 0, 2)  RED16(hp03, 0, 3)
    RED16(hp10, 16, 0) RED16(hp11, 16, 1) RED16(hp12, 16, 2) RED16(hp13, 16, 3)
    #undef RED16
    __syncthreads();

    if (t < 32) {
      float m_ = 0.f, q_ = 0.f;
#pragma unroll
      for (int b2 = 0; b2 < 8; ++b2) { m_ += part_s[t * 8 + b2]; q_ += part_q[t * 8 + b2]; }
      const float mean = m_ * (1.0f / DIM);
      const float var  = q_ * (1.0f / DIM) - mean * mean;
      smean[t] = mean;
      srstd[t] = rsqrtf(var + 1e-5f);
    }
    __syncthreads();

    #define WB(V, MBASE, J)                                                    \
    {                                                                          \
      const int m_ = (MBASE) + g * 4 + (J);                                    \
      const float hn_ = ((V) - smean[m_]) * srstd[m_] * sg[dd] + sbt[dd];      \
      sh[m_ * SHS + dd] = hn_;                                                 \
      const unsigned short bv_ = f2bf(hn_);                                    \
      hbf[m_ * SBS + dd] = bv_;                                                \
      hbT[dd * STS + m_] = bv_;                                                \
    }
    WB(hp00, 0, 0)  WB(hp01, 0, 1)  WB(hp02, 0, 2)  WB(hp03, 0, 3)
    WB(hp10, 16, 0) WB(hp11, 16, 1) WB(hp12, 16, 2) WB(hp13, 16, 3)
    #undef WB
    __syncthreads();
  }

  // ---------------- head -----------------------------------------------------
  if (t < DIM) {
    float s = 0.f, mx = -INFINITY;
#pragma unroll
    for (int n2 = 0; n2 < N_NODES; ++n2) {
      const float v = sh[n2 * SHS + t];
      s += v; mx = fmaxf(mx, v);
    }
    pooled[t]       = s * (1.0f / N_NODES);
    pooled[t + DIM] = mx;
  }
  __syncthreads();

  if (t < DIM) {
    const float4* w4f = (const float4*)(p.fc1_w + t * 2 * DIM);
    const float4* p4  = (const float4*)pooled;
    float acc = p.fc1_b[t];
#pragma unroll 8
    for (int k = 0; k < 2 * DIM / 4; ++k) {
      const float4 wv = w4f[k]; const float4 pv = p4[k];
      acc = fmaf(wv.x, pv.x, acc);
      acc = fmaf(wv.y, pv.y, acc);
      acc = fmaf(wv.z, pv.z, acc);
      acc = fmaf(wv.w, pv.w, acc);
    }
    svals[t] = acc;
  }
  __syncthreads();

  if (t < DIM) {
    float s = svals[t];
#pragma unroll
    for (int o = 32; o > 0; o >>= 1) s += __shfl_down(s, o, 64);
    if ((t & 63) == 0) red[t >> 6] = s;
  }
  __syncthreads();
  const float mean2 = (red[0] + red[1]) * (1.0f / DIM);
  if (t < DIM) {
    const float dx = svals[t] - mean2;
    float s = dx * dx;
#pragma unroll
    for (int o = 32; o > 0; o >>= 1) s += __shfl_down(s, o, 64);
    if ((t & 63) == 0) red[2 + (t >> 6)] = s;
  }
  __syncthreads();
  const float var2  = (red[2] + red[3]) * (1.0f / DIM);
  const float rstd2 = rsqrtf(var2 + 1e-5f);
  __syncthreads();
  if (t < DIM) {
    float x = (svals[t] - mean2) * rstd2 * p.ln2_g[t] + p.ln2_b[t];
    x = fmaxf(x, 0.f);
    float s = x * p.fc2_w[t];
#pragma unroll
    for (int o = 32; o > 0; o >>= 1) s += __shfl_down(s, o, 64);
    if ((t & 63) == 0) red[t >> 6] = s;
  }
  __syncthreads();
  if (t == 0) p.out[0] = red[0] + red[1] + p.fc2_b[0];
}

// ---------------------------------------------------------------------------
extern "C" void kernel_launch(void* const* d_in, const int* in_sizes, int n_in,
                              void* d_out, int out_size, void* d_ws, size_t ws_size,
                              hipStream_t stream)
{
  const int*   nt    = (const int*)d_in[0];
  const int*   tr    = (const int*)d_in[1];
  const int*   es    = (const int*)d_in[2];
  const int*   ed    = (const int*)d_in[3];
  const int*   ef    = (const int*)d_in[4];
  const float* ne_w  = (const float*)d_in[5];
  const float* te_w  = (const float*)d_in[6];
  const float* ef_w  = (const float*)d_in[7];
  const float* w_ih  = (const float*)d_in[8];
  const float* w_hh  = (const float*)d_in[9];
  const float* b_ih  = (const float*)d_in[10];
  const float* b_hh  = (const float*)d_in[11];
  const float* ln_g  = (const float*)d_in[12];
  const float* ln_b  = (const float*)d_in[13];
  const float* fc1_w = (const float*)d_in[14];
  const float* fc1_b = (const float*)d_in[15];
  const float* ln2_g = (const float*)d_in[16];
  const float* ln2_b = (const float*)d_in[17];
  const float* fc2_w = (const float*)d_in[18];
  const float* fc2_b = (const float*)d_in[19];

  const int E = in_sizes[2];

  // ws: hA[1024]@0 | hF[192]@4096 | pack(bf16 192KB)@8192
  int*            hA   = (int*)d_ws;
  int*            hF   = (int*)((char*)d_ws + 4096);
  unsigned short* pack = (unsigned short*)((char*)d_ws + 8192);

  hipMemsetAsync(d_ws, 0, 4864, stream);

  hipLaunchKernelGGL(hist_kernel, dim3(HIST_BLOCKS), dim3(NTHR_H), 0, stream,
                     es, ed, ef, E, hA, hF);
  hipLaunchKernelGGL(pack_kernel, dim3(PACK_BLOCKS), dim3(NTHR_P), 0, stream,
                     w_ih, w_hh, pack);

  GnnParams prm;
  prm.nt = nt; prm.tr = tr;
  prm.ne_w = ne_w; prm.te_w = te_w; prm.ef_w = ef_w;
  prm.b_ih = b_ih; prm.b_hh = b_hh;
  prm.ln_g = ln_g; prm.ln_b = ln_b;
  prm.fc1_w = fc1_w; prm.fc1_b = fc1_b;
  prm.ln2_g = ln2_g; prm.ln2_b = ln2_b;
  prm.fc2_w = fc2_w; prm.fc2_b = fc2_b;
  prm.hA = hA; prm.hF = hF; prm.pack = pack;
  prm.out = (float*)d_out;

  hipLaunchKernelGGL(gnn_kernel, dim3(1), dim3(NTHR_G), 0, stream, prm);
}

// Round 9
// 46.994 us; speedup vs baseline: 2.6913x; 1.1637x over previous
//
#include <hip/hip_runtime.h>
#include <math.h>

#define N_NODES 32
#define DIM     128
#define NTHR_H  256
#define HIST_BLOCKS 64
#define NTHR_P  256
#define PACK_BLOCKS 48
#define NTHR_G  512   // 8 waves, single workgroup, 2 waves/SIMD -> 256 VGPR budget

#define SHS 132   // fp32 row stride (elements)
#define SBS 136   // bf16 row stride (elements; 272 B)
#define STS 40    // bf16 transposed stride (80 B)

typedef __attribute__((ext_vector_type(8))) short bf16x8;
typedef __attribute__((ext_vector_type(4))) float f32x4;

// round-to-nearest-even f32 -> bf16 bits (finite values only)
__device__ __forceinline__ unsigned short f2bf(float f) {
  unsigned int u = __float_as_uint(f);
  u += 0x7fffu + ((u >> 16) & 1u);
  return (unsigned short)(u >> 16);
}

#define LOG2E 1.44269504088896340736f
__device__ __forceinline__ float fexp2(float x) { return __builtin_amdgcn_exp2f(x); }
__device__ __forceinline__ float frcp(float x)  { return __builtin_amdgcn_rcpf(x); }
__device__ __forceinline__ float sigm(float x)  { return frcp(1.f + fexp2(-LOG2E * x)); }
__device__ __forceinline__ float ftanh(float x) { return 1.f - 2.f * frcp(1.f + fexp2((2.f * LOG2E) * x)); }

// ---------------- histogram over edges (index-only, loop-invariant) ---------
__global__ __launch_bounds__(NTHR_H) void hist_kernel(
    const int* __restrict__ es, const int* __restrict__ ed,
    const int* __restrict__ ef, int E,
    int* __restrict__ hA, int* __restrict__ hF)
{
  __shared__ int lA[N_NODES * N_NODES];
  __shared__ int lF[N_NODES * 6];
  const int t = threadIdx.x;
  for (int i = t; i < N_NODES * N_NODES; i += NTHR_H) lA[i] = 0;
  for (int i = t; i < N_NODES * 6;       i += NTHR_H) lF[i] = 0;
  __syncthreads();

  const int E4 = E >> 2;
  const int4* es4 = (const int4*)es;
  const int4* ed4 = (const int4*)ed;
  const int4* ef4 = (const int4*)ef;
  #define DO_EDGE(S, D, F) \
    if ((unsigned)(S) < N_NODES && (unsigned)(D) < N_NODES) { \
      atomicAdd(&lA[(D) * N_NODES + (S)], 1); \
      atomicAdd(&lF[(D) * 6 + (F)], 1); }
  for (int i = blockIdx.x * NTHR_H + t; i < E4; i += gridDim.x * NTHR_H) {
    int4 s4 = es4[i], d4 = ed4[i], f4 = ef4[i];
    DO_EDGE(s4.x, d4.x, f4.x)
    DO_EDGE(s4.y, d4.y, f4.y)
    DO_EDGE(s4.z, d4.z, f4.z)
    DO_EDGE(s4.w, d4.w, f4.w)
  }
  if (blockIdx.x == 0) {
    for (int e = (E4 << 2) + t; e < E; e += NTHR_H) {
      int s = es[e], d = ed[e], f = ef[e];
      DO_EDGE(s, d, f)
    }
  }
  #undef DO_EDGE
  __syncthreads();
  for (int i = t; i < N_NODES * N_NODES; i += NTHR_H) { int v = lA[i]; if (v) atomicAdd(&hA[i], v); }
  for (int i = t; i < N_NODES * 6;       i += NTHR_H) { int v = lF[i]; if (v) atomicAdd(&hF[i], v); }
}

// ------- pack [w_ih;w_hh] (768x128 fp32) into bf16 B-fragments; zero hA/hF --
// B-frag for mfma_f32_16x16x32_bf16: lane l holds B[k][n] with n = l&15,
// k = (l>>4)*8 + j. Tile T = mm*96 + nt*4 + kt.
__global__ __launch_bounds__(NTHR_P) void pack_kernel(
    const float* __restrict__ w_ih, const float* __restrict__ w_hh,
    unsigned short* __restrict__ pack,
    int* __restrict__ hA, int* __restrict__ hF)
{
  if (blockIdx.x == 0) {   // zero the histogram outputs (hist runs after us)
    for (int i = threadIdx.x; i < N_NODES * N_NODES; i += NTHR_P) hA[i] = 0;
    for (int i = threadIdx.x; i < N_NODES * 6;       i += NTHR_P) hF[i] = 0;
  }
  const int gid = blockIdx.x * NTHR_P + threadIdx.x;  // 0..12287
  const int T = gid >> 6;          // 0..191
  const int l = gid & 63;
  const int mm = T / 96;           // 0 = w_ih, 1 = w_hh
  const int t2 = T % 96;
  const int nt = t2 >> 2;          // 0..23 row-tile over 384
  const int kt = t2 & 3;
  const int row = nt * 16 + (l & 15);
  const int k   = kt * 32 + (l >> 4) * 8;
  const float* src = (mm ? w_hh : w_ih) + row * DIM + k;
  bf16x8 out;
#pragma unroll
  for (int j = 0; j < 8; ++j) out[j] = (short)f2bf(src[j]);
  *(bf16x8*)(pack + (size_t)T * 512 + l * 8) = out;
}

// --------- single-workgroup GRU: weights + h in registers -------------------
struct GnnParams {
  const int* nt; const int* tr;
  const float* ne_w; const float* te_w; const float* ef_w;
  const float* b_ih; const float* b_hh;
  const float* ln_g; const float* ln_b;
  const float* fc1_w; const float* fc1_b;
  const float* ln2_g; const float* ln2_b;
  const float* fc2_w; const float* fc2_b;
  const int* hA; const int* hF;
  const unsigned short* pack;
  float* out;
};

__global__ __launch_bounds__(NTHR_G, 2) void gnn_kernel(GnnParams p)
{
  const int t = threadIdx.x;
  const int nb = t >> 6;          // wave 0..7 (= dim-tile)
  const int l = t & 63;
  const int g = l >> 4;           // 0..3
  const int ln16 = l & 15;
  const int dd = nb * 16 + ln16;  // this lane's dim

  __shared__ __align__(16) float sh[N_NODES * SHS];        // final h (for head)
  __shared__ __align__(16) float sBnorm[N_NODES * SHS];    // (F@ef_w)/cnt
  __shared__ __align__(16) unsigned short hbf [N_NODES * SBS]; // bf16 h
  __shared__ __align__(16) unsigned short hagg[N_NODES * SBS]; // bf16 agg
  __shared__ __align__(16) unsigned short hbT [DIM * STS];     // bf16 h^T
  __shared__ __align__(16) unsigned short anormP[2 * 64 * 8];  // A-frags A/cnt
  __shared__ __align__(16) float part_s[N_NODES * 8];
  __shared__ __align__(16) float part_q[N_NODES * 8];
  __shared__ float sicnt[N_NODES];
  __shared__ int   shF[192], snt[N_NODES], str[N_NODES];
  __shared__ float pooled[2 * DIM], svals[DIM], red[4];

  // ---- early independent global loads (latency overlaps init) --------------
  bf16x8 Bw[6][4];
#pragma unroll
  for (int q = 0; q < 6; ++q)
#pragma unroll
    for (int kt = 0; kt < 4; ++kt) {
      const int T = (q < 3) ? ((q * 8 + nb) * 4 + kt)
                            : (96 + ((q - 3) * 8 + nb) * 4 + kt);
      Bw[q][kt] = *(const bf16x8*)(p.pack + (size_t)T * 512 + (size_t)l * 8);
    }
  const float bi0 = p.b_ih[dd], bi1 = p.b_ih[DIM + dd], bi2 = p.b_ih[2 * DIM + dd];
  const float bh0 = p.b_hh[dd], bh1 = p.b_hh[DIM + dd], bh2 = p.b_hh[2 * DIM + dd];
  const float gdd = p.ln_g[dd], bdd = p.ln_b[dd];

  // ---- stage small tables ---------------------------------------------------
  if (t < 32) { snt[t] = p.nt[t]; str[t] = p.tr[t]; }
  if (t < 192) shF[t] = p.hF[t];
  if (t < 32) {
    int c = 0;
    for (int s = 0; s < 32; ++s) c += p.hA[t * 32 + s];
    sicnt[t] = 1.0f / fmaxf((float)c, 1.0f);
  }
  __syncthreads();

  // h0 (bf16 copies) + Bnorm
  for (int i = t; i < N_NODES * DIM; i += NTHR_G) {
    const int n = i >> 7, d2 = i & (DIM - 1);
    const float v = p.ne_w[snt[n] * DIM + d2] + p.te_w[str[n] * DIM + d2];
    const unsigned short bv = f2bf(v);
    hbf[n * SBS + d2] = bv;
    hbT[d2 * STS + n] = bv;
    float acc = 0.f;
#pragma unroll
    for (int f = 0; f < 6; ++f)
      acc = fmaf((float)shF[n * 6 + f], p.ef_w[f * DIM + d2], acc);
    sBnorm[n * SHS + d2] = acc * sicnt[n];
  }
  if (t < 128) {                      // pack Anorm A-fragments (2 m-tiles)
    const int mt = t >> 6, ll = t & 63;
    const int m = mt * 16 + (ll & 15);
    const float ic = sicnt[m];
#pragma unroll
    for (int j = 0; j < 8; ++j) {
      const int s = (ll >> 4) * 8 + j;
      anormP[(mt * 64 + ll) * 8 + j] = f2bf((float)p.hA[m * 32 + s] * ic);
    }
  }

  // h kept in registers: this thread owns nodes {mt*16+g*4+j} at dim dd
  float hv00, hv01, hv02, hv03, hv10, hv11, hv12, hv13;
  float hp00, hp01, hp02, hp03, hp10, hp11, hp12, hp13;
  #define FOREACH8(M) M(0,0,hv00,hp00) M(0,1,hv01,hp01) M(0,2,hv02,hp02) M(0,3,hv03,hp03) \
                      M(1,0,hv10,hp10) M(1,1,hv11,hp11) M(1,2,hv12,hp12) M(1,3,hv13,hp13)
  #define HV_INIT(MT,J,HV,HP) \
    HV = p.ne_w[snt[MT*16 + g*4 + J] * DIM + dd] + p.te_w[str[MT*16 + g*4 + J] * DIM + dd];
  FOREACH8(HV_INIT)
  #undef HV_INIT
  __syncthreads();

  // loop-invariant register caches
  const bf16x8 aN0 = *(const bf16x8*)&anormP[l * 8];
  const bf16x8 aN1 = *(const bf16x8*)&anormP[(64 + l) * 8];
  f32x4 cB0, cB1;
#pragma unroll
  for (int j = 0; j < 4; ++j) {
    cB0[j] = sBnorm[(g * 4 + j) * SHS + dd];
    cB1[j] = sBnorm[(16 + g * 4 + j) * SHS + dd];
  }
  const f32x4 fz = {0.f, 0.f, 0.f, 0.f};

  // ---------------- 5 GRU iterations ----------------------------------------
  for (int it = 0; it < 5; ++it) {
    // Phase A: agg = Anorm@H + Bnorm (A-frags & C in regs, B from hbT)
    {
      const bf16x8 bT = *(const bf16x8*)&hbT[dd * STS + g * 8];
      const f32x4 d0 = __builtin_amdgcn_mfma_f32_16x16x32_bf16(aN0, bT, cB0, 0, 0, 0);
      const f32x4 d1 = __builtin_amdgcn_mfma_f32_16x16x32_bf16(aN1, bT, cB1, 0, 0, 0);
#pragma unroll
      for (int j = 0; j < 4; ++j) {
        hagg[(g * 4 + j) * SBS + dd]      = f2bf(d0[j]);
        hagg[(16 + g * 4 + j) * SBS + dd] = f2bf(d1[j]);
      }
    }
    __syncthreads();   // hagg ready; prev-iter hbf writes visible

    // Phase B: C_ih = agg@w_ih^T, C_hh = h@w_hh^T — all weights in VGPRs
    f32x4 Ai[2][3], Hh[2][3];
#pragma unroll
    for (int mt = 0; mt < 2; ++mt)
#pragma unroll
      for (int q = 0; q < 3; ++q) { Ai[mt][q] = fz; Hh[mt][q] = fz; }
#pragma unroll
    for (int kt = 0; kt < 4; ++kt) {
      const int ko = kt * 32 + g * 8;
      const bf16x8 ai0 = *(const bf16x8*)&hagg[ln16        * SBS + ko];
      const bf16x8 ai1 = *(const bf16x8*)&hagg[(16 + ln16) * SBS + ko];
      const bf16x8 ah0 = *(const bf16x8*)&hbf [ln16        * SBS + ko];
      const bf16x8 ah1 = *(const bf16x8*)&hbf [(16 + ln16) * SBS + ko];
#pragma unroll
      for (int q = 0; q < 3; ++q) {
        Ai[0][q] = __builtin_amdgcn_mfma_f32_16x16x32_bf16(ai0, Bw[q][kt],     Ai[0][q], 0, 0, 0);
        Ai[1][q] = __builtin_amdgcn_mfma_f32_16x16x32_bf16(ai1, Bw[q][kt],     Ai[1][q], 0, 0, 0);
        Hh[0][q] = __builtin_amdgcn_mfma_f32_16x16x32_bf16(ah0, Bw[3 + q][kt], Hh[0][q], 0, 0, 0);
        Hh[1][q] = __builtin_amdgcn_mfma_f32_16x16x32_bf16(ah1, Bw[3 + q][kt], Hh[1][q], 0, 0, 0);
      }
    }

    // Phase C: gates in registers (D-layout: dim = l&15, node = g*4+j)
    #define GATE(MT,J,HV,HP)                                                   \
    {                                                                          \
      const float r_ = sigm(Ai[MT][0][J] + bi0 + Hh[MT][0][J] + bh0);          \
      const float z_ = sigm(Ai[MT][1][J] + bi1 + Hh[MT][1][J] + bh1);          \
      const float n_ = ftanh(Ai[MT][2][J] + bi2 + r_ * (Hh[MT][2][J] + bh2));  \
      HP = (1.f - z_) * n_ + z_ * HV;                                          \
    }
    FOREACH8(GATE)
    #undef GATE

    // LN partials across the 16 dim-lanes of this wave
    #define RED16(MT,J,HV,HP)                                                  \
    {                                                                          \
      float s_ = HP, q_ = HP * HP;                                             \
      s_ += __shfl_xor(s_, 1, 16);  q_ += __shfl_xor(q_, 1, 16);               \
      s_ += __shfl_xor(s_, 2, 16);  q_ += __shfl_xor(q_, 2, 16);               \
      s_ += __shfl_xor(s_, 4, 16);  q_ += __shfl_xor(q_, 4, 16);               \
      s_ += __shfl_xor(s_, 8, 16);  q_ += __shfl_xor(q_, 8, 16);               \
      if (ln16 == 0) {                                                         \
        const int m_ = MT * 16 + g * 4 + J;                                    \
        part_s[m_ * 8 + nb] = s_;  part_q[m_ * 8 + nb] = q_;                   \
      }                                                                        \
    }
    FOREACH8(RED16)
    #undef RED16
    __syncthreads();   // partials visible

    // per-thread mean/rstd + LN write-back (h stays in regs; LDS bf16 copies)
    #define FIN(MT,J,HV,HP)                                                    \
    {                                                                          \
      const int m_ = MT * 16 + g * 4 + J;                                      \
      const float4 s0 = *(const float4*)&part_s[m_ * 8];                       \
      const float4 s1 = *(const float4*)&part_s[m_ * 8 + 4];                   \
      const float4 q0 = *(const float4*)&part_q[m_ * 8];                       \
      const float4 q1 = *(const float4*)&part_q[m_ * 8 + 4];                   \
      const float mean = (((s0.x + s0.y) + (s0.z + s0.w)) +                    \
                          ((s1.x + s1.y) + (s1.z + s1.w))) * (1.0f / DIM);     \
      const float var  = (((q0.x + q0.y) + (q0.z + q0.w)) +                    \
                          ((q1.x + q1.y) + (q1.z + q1.w))) * (1.0f / DIM)      \
                         - mean * mean;                                        \
      const float rstd = rsqrtf(var + 1e-5f);                                  \
      const float hn_ = (HP - mean) * rstd * gdd + bdd;                        \
      HV = hn_;                                                                \
      const unsigned short bv_ = f2bf(hn_);                                    \
      hbf[m_ * SBS + dd] = bv_;                                                \
      hbT[dd * STS + m_] = bv_;                                                \
      if (it == 4) sh[m_ * SHS + dd] = hn_;                                    \
    }
    FOREACH8(FIN)
    #undef FIN
    // no sync needed here: next Phase A touches only own-wave hbT rows;
    // cross-wave hbf/hagg consumers are fenced by the Phase-A sync.
  }
  __syncthreads();   // sh complete for head
  #undef FOREACH8

  // ---------------- head -----------------------------------------------------
  if (t < DIM) {
    float s = 0.f, mx = -INFINITY;
#pragma unroll
    for (int n2 = 0; n2 < N_NODES; ++n2) {
      const float v = sh[n2 * SHS + t];
      s += v; mx = fmaxf(mx, v);
    }
    pooled[t]       = s * (1.0f / N_NODES);
    pooled[t + DIM] = mx;
  }
  __syncthreads();

  if (t < DIM) {
    const float4* w4f = (const float4*)(p.fc1_w + t * 2 * DIM);
    const float4* p4  = (const float4*)pooled;
    float acc = p.fc1_b[t];
#pragma unroll 8
    for (int k = 0; k < 2 * DIM / 4; ++k) {
      const float4 wv = w4f[k]; const float4 pv = p4[k];
      acc = fmaf(wv.x, pv.x, acc);
      acc = fmaf(wv.y, pv.y, acc);
      acc = fmaf(wv.z, pv.z, acc);
      acc = fmaf(wv.w, pv.w, acc);
    }
    svals[t] = acc;
  }
  __syncthreads();

  if (t < DIM) {
    float s = svals[t];
#pragma unroll
    for (int o = 32; o > 0; o >>= 1) s += __shfl_down(s, o, 64);
    if ((t & 63) == 0) red[t >> 6] = s;
  }
  __syncthreads();
  const float mean2 = (red[0] + red[1]) * (1.0f / DIM);
  if (t < DIM) {
    const float dx = svals[t] - mean2;
    float s = dx * dx;
#pragma unroll
    for (int o = 32; o > 0; o >>= 1) s += __shfl_down(s, o, 64);
    if ((t & 63) == 0) red[2 + (t >> 6)] = s;
  }
  __syncthreads();
  const float var2  = (red[2] + red[3]) * (1.0f / DIM);
  const float rstd2 = rsqrtf(var2 + 1e-5f);
  __syncthreads();
  if (t < DIM) {
    float x = (svals[t] - mean2) * rstd2 * p.ln2_g[t] + p.ln2_b[t];
    x = fmaxf(x, 0.f);
    float s = x * p.fc2_w[t];
#pragma unroll
    for (int o = 32; o > 0; o >>= 1) s += __shfl_down(s, o, 64);
    if ((t & 63) == 0) red[t >> 6] = s;
  }
  __syncthreads();
  if (t == 0) p.out[0] = red[0] + red[1] + p.fc2_b[0];
}

// ---------------------------------------------------------------------------
extern "C" void kernel_launch(void* const* d_in, const int* in_sizes, int n_in,
                              void* d_out, int out_size, void* d_ws, size_t ws_size,
                              hipStream_t stream)
{
  const int*   nt    = (const int*)d_in[0];
  const int*   tr    = (const int*)d_in[1];
  const int*   es    = (const int*)d_in[2];
  const int*   ed    = (const int*)d_in[3];
  const int*   ef    = (const int*)d_in[4];
  const float* ne_w  = (const float*)d_in[5];
  const float* te_w  = (const float*)d_in[6];
  const float* ef_w  = (const float*)d_in[7];
  const float* w_ih  = (const float*)d_in[8];
  const float* w_hh  = (const float*)d_in[9];
  const float* b_ih  = (const float*)d_in[10];
  const float* b_hh  = (const float*)d_in[11];
  const float* ln_g  = (const float*)d_in[12];
  const float* ln_b  = (const float*)d_in[13];
  const float* fc1_w = (const float*)d_in[14];
  const float* fc1_b = (const float*)d_in[15];
  const float* ln2_g = (const float*)d_in[16];
  const float* ln2_b = (const float*)d_in[17];
  const float* fc2_w = (const float*)d_in[18];
  const float* fc2_b = (const float*)d_in[19];

  const int E = in_sizes[2];

  // ws: hA[1024]@0 | hF[192]@4096 | pack(bf16 192KB)@8192
  int*            hA   = (int*)d_ws;
  int*            hF   = (int*)((char*)d_ws + 4096);
  unsigned short* pack = (unsigned short*)((char*)d_ws + 8192);

  // pack also zeroes hA/hF (stream order: pack -> hist -> gnn)
  hipLaunchKernelGGL(pack_kernel, dim3(PACK_BLOCKS), dim3(NTHR_P), 0, stream,
                     w_ih, w_hh, pack, hA, hF);
  hipLaunchKernelGGL(hist_kernel, dim3(HIST_BLOCKS), dim3(NTHR_H), 0, stream,
                     es, ed, ef, E, hA, hF);

  GnnParams prm;
  prm.nt = nt; prm.tr = tr;
  prm.ne_w = ne_w; prm.te_w = te_w; prm.ef_w = ef_w;
  prm.b_ih = b_ih; prm.b_hh = b_hh;
  prm.ln_g = ln_g; prm.ln_b = ln_b;
  prm.fc1_w = fc1_w; prm.fc1_b = fc1_b;
  prm.ln2_g = ln2_g; prm.ln2_b = ln2_b;
  prm.fc2_w = fc2_w; prm.fc2_b = fc2_b;
  prm.hA = hA; prm.hF = hF; prm.pack = pack;
  prm.out = (float*)d_out;

  hipLaunchKernelGGL(gnn_kernel, dim3(1), dim3(NTHR_G), 0, stream, prm);
}